// Round 3
// baseline (168.682 us; speedup 1.0000x reference)
//
#include <hip/hip_runtime.h>
#include <hip/hip_bf16.h>

typedef unsigned int u32;
typedef unsigned short u16;
typedef unsigned long long u64;

// ---------------- packed-weight layout in d_ws (u64 indices) ----------------
#define OC1 0      // conv1: 3 nz ch-pair words, then 3 sign ch-pair words
#define OC2 8      // conv2: per out-ch 6 u64: [0..2]=nz rows, [3..5]=sign rows
#define WCONV 104
#define OF1 104    // fc1: per j (pad 128): 0..6 nz, 7..13 sign, 14 pad
#define OF2 2024   // fc2: per j (pad 128): [0,1] nz, [2,3] sign, [4] pad
#define OF3 2664   // fc3: per j: [0,1] nz, [2,3] sign
#define WTOT 2704

__global__ void pack_w(const float* __restrict__ w1, const float* __restrict__ w2,
                       const float* __restrict__ f1, const float* __restrict__ f2,
                       const float* __restrict__ f3, u64* __restrict__ P) {
    int g = blockIdx.x * 256 + threadIdx.x;
    if (g < 1920) {                      // fc1: j*15 + w
        int j = g / 15, w = g % 15;
        u64 v = 0;
        if (w < 14 && j < 120) {
            bool sp = (w >= 7); int k = sp ? w - 7 : w;
            for (int f = 0; f < 4; f++) {
                int p = 4 * k + f;
                if (p < 25)
                    for (int ch = 0; ch < 16; ch++) {
                        float x = f1[j * 400 + ch * 25 + p];
                        bool b = sp ? (x < 0.0f) : (x != 0.0f);
                        if (b) v |= 1ull << (f * 16 + ch);
                    }
            }
        }
        P[OF1 + g] = v;
    } else if (g < 2560) {               // fc2
        int g2 = g - 1920, j = g2 / 5, w = g2 % 5;
        u64 v = 0;
        if (w < 4 && j < 84) {
            bool sp = (w >= 2); int h = w & 1;
            for (int b = 0; b < 64; b++) {
                int k = h * 64 + b;
                if (k < 120) {
                    float x = f2[j * 120 + k];
                    bool bb = sp ? (x < 0.0f) : (x != 0.0f);
                    if (bb) v |= 1ull << b;
                }
            }
        }
        P[OF2 + g2] = v;
    } else if (g < 2600) {               // fc3
        int g3 = g - 2560, j = g3 / 4, w = g3 % 4;
        bool sp = (w >= 2); int h = w & 1;
        u64 v = 0;
        for (int b = 0; b < 64; b++) {
            int k = h * 64 + b;
            if (k < 84) {
                float x = f3[j * 84 + k];
                bool bb = sp ? (x < 0.0f) : (x != 0.0f);
                if (bb) v |= 1ull << b;
            }
        }
        P[OF3 + g3] = v;
    } else if (g < 2696) {               // conv2
        int c = g - 2600, ch = c / 6, w = c % 6;
        bool sp = (w >= 3); int wp = w % 3;
        u64 v = 0;
        for (int half = 0; half < 2; half++) {
            int r = 2 * wp + half;
            if (r < 5) {
                u32 rowv = 0;
                for (int ci = 0; ci < 6; ci++)
                    for (int cc = 0; cc < 5; cc++) {
                        float x = w2[((ch * 6 + ci) * 5 + r) * 5 + cc];
                        bool b = sp ? (x < 0.0f) : (x != 0.0f);
                        int bit = (ci < 3) ? (5 * ci + cc) : (15 + 5 * (ci - 3) + cc);
                        if (b) rowv |= 1u << bit;
                    }
                v |= (u64)rowv << (32 * half);
            }
        }
        P[OC2 + ch * 6 + (sp ? 3 : 0) + wp] = v;
    } else if (g < 2702) {               // conv1
        int c = g - 2696;
        int pair = c % 3; bool sp = (c >= 3);
        u64 v = 0;
        for (int half = 0; half < 2; half++) {
            int ch = 2 * pair + half;
            u32 wd = 0;
            for (int r = 0; r < 5; r++)
                for (int cc = 0; cc < 5; cc++) {
                    float x = w1[ch * 25 + r * 5 + cc];
                    bool b = sp ? (x < 0.0f) : (x != 0.0f);
                    if (b) wd |= 1u << (6 * r + cc);
                }
            v |= (u64)wd << (32 * half);
        }
        P[OC1 + (sp ? 3 : 0) + pair] = v;
    }
}

#define G 8  // images per block (2 per wave, 4 waves)

__device__ __forceinline__ u32 sgnb(int v) { return (u32)v >> 31; }
__device__ __forceinline__ u32 nzb(int v)  { return (u32)(v | -v) >> 31; }
// Within one wave the DS pipe is FIFO, so read-after-write through LDS needs
// only a compiler scheduling fence, not s_barrier:
#define WB() __builtin_amdgcn_wave_barrier()

// Per wave: load imgA -> pack A -> issue imgB loads -> conv1(A) [B streams
// underneath] -> pack B -> conv1(B) -> conv2 -> fc. Straight-line code so the
// 16-VGPR prefetch has a simple live range (round-1 scratch lesson). Slow
// (zero-containing) path is register-light LDS-rereading so it doesn't set
// the static VGPR peak; it never runs on sign-clean data.
__global__ __launch_bounds__(256, 8) void lenet_main(const float* __restrict__ X,
                                                     const u64* __restrict__ P,
                                                     float* __restrict__ out) {
    __shared__ u32 xs[G][32], xn[G][32];
    __shared__ u64 h1An[G][14], h1As[G][14], h1Bn[G][14], h1Bs[G][14];
    __shared__ u64 h2n[G][7], h2s[G][7];
    __shared__ u64 f1s[G][2], f1n[G][2], f2s[G][2], f2n[G][2];

    const int tid = threadIdx.x;
    const int wid = tid >> 6, lane = tid & 63;
    const int img0 = blockIdx.x * G;
    const int liA = wid * 2, liB = liA + 1;
    const int li0 = liA;

    const float4* X4 = (const float4*)(X + (size_t)img0 * 1024);

    // ---- issue image-A loads (16 VGPR) ----
    float4 rvA[4];
    #pragma unroll
    for (int it = 0; it < 4; it++) rvA[it] = X4[liA * 256 + it * 64 + lane];

    // ---- weight cleanliness (no exact-0 conv weights), wave-uniform ----
    u64 db;
    {
        bool bad = false;
        if (lane < 51) {
            u64 w, exp;
            if (lane < 48) {
                int ch = lane / 3, k = lane % 3;
                w = P[OC2 + ch * 6 + k];
                exp = (k < 2) ? 0x3FFFFFFF3FFFFFFFull : 0x000000003FFFFFFFull;
            } else {
                w = P[OC1 + (lane - 48)];
                exp = 0x1F7DF7DF1F7DF7DFull;
            }
            bad = (w != exp);
        }
        db = __ballot(bad);
    }

    // ---- conv1 helpers (instantiated per image) ----
    auto conv1_fast = [&](int li) {
        const int px = lane & 15;
        const int pxe = px < 14 ? px : 13;
        const int tt = 2 * pxe;
        const int g = lane >> 4;
        u64 c1s0 = P[OC1 + 3], c1s1 = P[OC1 + 4], c1s2 = P[OC1 + 5]; // uniform->SGPR
        #pragma unroll
        for (int it = 0; it < 4; it++) {
            int seg = it * 4 + g;              // 0..15, 14..15 are dummies
            int py = seg < 14 ? seg : 13;
            int oy = 2 * py;
            u32 rs[6];
            #pragma unroll
            for (int k = 0; k < 6; k++) rs[k] = xs[li][oy + k];
            // 6-bit-field packed windows: dx=0/1 share one extraction
            u32 W6a = 0;
            #pragma unroll
            for (int r = 0; r < 5; r++) W6a |= ((rs[r] >> tt) & 63u) << (6 * r);
            u32 W6b = (W6a >> 6) | (((rs[5] >> tt) & 63u) << 24);
            u32 cnt[6];
            #pragma unroll
            for (int c = 0; c < 6; c++) cnt[c] = 255;
            #pragma unroll
            for (int dy = 0; dy < 2; dy++) {
                u32 base = dy ? W6b : W6a;
                #pragma unroll
                for (int dx = 0; dx < 2; dx++) {
                    u32 w = (dx ? (base >> 1) : base) & 0x1F7DF7DFu;
                    u64 W = ((u64)w << 32) | w;
                    u64 t0 = W ^ c1s0;
                    cnt[0] = min(cnt[0], (u32)__popc((u32)t0));
                    cnt[1] = min(cnt[1], (u32)__popc((u32)(t0 >> 32)));
                    u64 t1 = W ^ c1s1;
                    cnt[2] = min(cnt[2], (u32)__popc((u32)t1));
                    cnt[3] = min(cnt[3], (u32)__popc((u32)(t1 >> 32)));
                    u64 t2w = W ^ c1s2;
                    cnt[4] = min(cnt[4], (u32)__popc((u32)t2w));
                    cnt[5] = min(cnt[5], (u32)__popc((u32)(t2w >> 32)));
                }
            }
            u64 bS[6];
            #pragma unroll
            for (int c = 0; c < 6; c++) bS[c] = __ballot(cnt[c] >= 13);
            if (px == 0 && seg < 14) {
                int sh = lane & 48;
                u64 rAs = ((bS[0] >> sh) & 0x3FFF) | (((bS[1] >> sh) & 0x3FFF) << 16) | (((bS[2] >> sh) & 0x3FFF) << 32);
                u64 rBs = ((bS[3] >> sh) & 0x3FFF) | (((bS[4] >> sh) & 0x3FFF) << 16) | (((bS[5] >> sh) & 0x3FFF) << 32);
                h1As[li][seg] = rAs; h1Bs[li][seg] = rBs;
            }
        }
    };
    auto conv1_slow = [&](int li) {     // register-light; perf-irrelevant path
        const int px = lane & 15;
        const int pxe = px < 14 ? px : 13;
        const int tt = 2 * pxe;
        const int g = lane >> 4;
        for (int it = 0; it < 4; it++) {
            int seg = it * 4 + g;
            int py = seg < 14 ? seg : 13;
            int oy = 2 * py;
            int best[6];
            for (int c = 0; c < 6; c++) best[c] = -1000;
            for (int dy = 0; dy < 2; dy++)
                for (int dx = 0; dx < 2; dx++) {
                    u32 wn = 0, ws = 0;
                    for (int r = 0; r < 5; r++) {
                        u32 an = xn[li][oy + dy + r], as = xs[li][oy + dy + r];
                        wn |= ((an >> (tt + dx)) & 31u) << (6 * r);
                        ws |= ((as >> (tt + dx)) & 31u) << (6 * r);
                    }
                    u64 Wn = ((u64)wn << 32) | wn;
                    u64 Ws = ((u64)ws << 32) | ws;
                    for (int p = 0; p < 3; p++) {
                        u64 cn = P[OC1 + p], cs = P[OC1 + 3 + p];
                        u64 m  = Wn & cn;
                        u64 mx = m & (Ws ^ cs);
                        int a0 = __popc((u32)m) - 2 * __popc((u32)mx);
                        int a1 = __popc((u32)(m >> 32)) - 2 * __popc((u32)(mx >> 32));
                        best[2 * p]     = max(best[2 * p], a0);
                        best[2 * p + 1] = max(best[2 * p + 1], a1);
                    }
                }
            u64 bS[6], bN[6];
            for (int c = 0; c < 6; c++) {
                bS[c] = __ballot(best[c] < 0);
                bN[c] = __ballot(best[c] != 0);
            }
            if (px == 0 && seg < 14) {
                int sh = lane & 48;
                u64 rAs = ((bS[0] >> sh) & 0x3FFF) | (((bS[1] >> sh) & 0x3FFF) << 16) | (((bS[2] >> sh) & 0x3FFF) << 32);
                u64 rAn = ((bN[0] >> sh) & 0x3FFF) | (((bN[1] >> sh) & 0x3FFF) << 16) | (((bN[2] >> sh) & 0x3FFF) << 32);
                u64 rBs = ((bS[3] >> sh) & 0x3FFF) | (((bS[4] >> sh) & 0x3FFF) << 16) | (((bS[5] >> sh) & 0x3FFF) << 32);
                u64 rBn = ((bN[3] >> sh) & 0x3FFF) | (((bN[4] >> sh) & 0x3FFF) << 16) | (((bN[5] >> sh) & 0x3FFF) << 32);
                h1As[li][seg] = rAs; h1An[li][seg] = rAn;
                h1Bs[li][seg] = rBs; h1Bn[li][seg] = rBn;
            }
        }
    };

    // ---- pack A: nibble binarize + shfl-xor pack; zero-detect accumulated ----
    u32 naccA = 15u;
    #pragma unroll
    for (int it = 0; it < 4; it++) {
        float4 v = rvA[it];
        u32 s = (v.x < 0.0f ? 1u : 0u) | (v.y < 0.0f ? 2u : 0u)
              | (v.z < 0.0f ? 4u : 0u) | (v.w < 0.0f ? 8u : 0u);
        u32 n = (v.x != 0.0f ? 1u : 0u) | (v.y != 0.0f ? 2u : 0u)
              | (v.z != 0.0f ? 4u : 0u) | (v.w != 0.0f ? 8u : 0u);
        naccA &= n;
        u32 sw = s << (4 * (lane & 7));
        sw |= __shfl_xor((int)sw, 1); sw |= __shfl_xor((int)sw, 2); sw |= __shfl_xor((int)sw, 4);
        if ((lane & 7) == 0) xs[liA][it * 8 + (lane >> 3)] = sw;
    }
    const bool fpA = ((__ballot(naccA != 15u) | db) == 0);
    if (!fpA) {                        // rare: build the nonzero plane too
        #pragma unroll
        for (int it = 0; it < 4; it++) {
            float4 v = rvA[it];
            u32 n = (v.x != 0.0f ? 1u : 0u) | (v.y != 0.0f ? 2u : 0u)
                  | (v.z != 0.0f ? 4u : 0u) | (v.w != 0.0f ? 8u : 0u);
            u32 nw = n << (4 * (lane & 7));
            nw |= __shfl_xor((int)nw, 1); nw |= __shfl_xor((int)nw, 2); nw |= __shfl_xor((int)nw, 4);
            if ((lane & 7) == 0) xn[liA][it * 8 + (lane >> 3)] = nw;
        }
    }

    // ---- issue image-B loads; they stream under conv1(A) ----
    float4 rvB[4];
    #pragma unroll
    for (int it = 0; it < 4; it++) rvB[it] = X4[liB * 256 + it * 64 + lane];

    WB();
    if (fpA) conv1_fast(liA); else conv1_slow(liA);

    // ---- pack B ----
    u32 naccB = 15u;
    #pragma unroll
    for (int it = 0; it < 4; it++) {
        float4 v = rvB[it];
        u32 s = (v.x < 0.0f ? 1u : 0u) | (v.y < 0.0f ? 2u : 0u)
              | (v.z < 0.0f ? 4u : 0u) | (v.w < 0.0f ? 8u : 0u);
        u32 n = (v.x != 0.0f ? 1u : 0u) | (v.y != 0.0f ? 2u : 0u)
              | (v.z != 0.0f ? 4u : 0u) | (v.w != 0.0f ? 8u : 0u);
        naccB &= n;
        u32 sw = s << (4 * (lane & 7));
        sw |= __shfl_xor((int)sw, 1); sw |= __shfl_xor((int)sw, 2); sw |= __shfl_xor((int)sw, 4);
        if ((lane & 7) == 0) xs[liB][it * 8 + (lane >> 3)] = sw;
    }
    const bool fpB = ((__ballot(naccB != 15u) | db) == 0);
    if (!fpB) {
        #pragma unroll
        for (int it = 0; it < 4; it++) {
            float4 v = rvB[it];
            u32 n = (v.x != 0.0f ? 1u : 0u) | (v.y != 0.0f ? 2u : 0u)
                  | (v.z != 0.0f ? 4u : 0u) | (v.w != 0.0f ? 8u : 0u);
            u32 nw = n << (4 * (lane & 7));
            nw |= __shfl_xor((int)nw, 1); nw |= __shfl_xor((int)nw, 2); nw |= __shfl_xor((int)nw, 4);
            if ((lane & 7) == 0) xn[liB][it * 8 + (lane >> 3)] = nw;
        }
    }
    WB();
    if (fpB) conv1_fast(liB); else conv1_slow(liB);
    WB();

    // ---- conv2 + pool: 50 lanes (2 img x 25 points); per-lane u16 stores ----
    if (lane < 6) {   // zero the 3 pad halfwords (u16 idx 25..27) per image
        int li = li0 + (lane >= 3 ? 1 : 0); int t = lane % 3;
        ((u16*)h2n[li])[25 + t] = 0; ((u16*)h2s[li])[25 + t] = 0;
    }
    if (lane < 50) {
        int im = lane >= 25 ? 1 : 0, p = lane - 25 * im, li = li0 + im;
        bool cfast = im ? fpB : fpA;
        int py = p / 5, px2 = p % 5;
        int y0 = 2 * py;
        if (cfast) {
            u32 dsg[2][6];
            for (int r = 0; r < 6; r++) {
                u64 a = h1As[li][y0 + r], b = h1Bs[li][y0 + r];
                for (int dx = 0; dx < 2; dx++) {
                    int t2 = 2 * px2 + dx;
                    u64 as = a >> t2, bs = b >> t2;
                    dsg[dx][r] = (((u32)as & 31u) | ((u32)(as >> 11) & 0x3E0u) | ((u32)(as >> 22) & 0x7C00u))
                               | ((((u32)bs & 31u) | ((u32)(bs >> 11) & 0x3E0u) | ((u32)(bs >> 22) & 0x7C00u)) << 15);
                }
            }
            u64 Ps[2][4];
            for (int dx = 0; dx < 2; dx++)
                for (int r = 0; r < 4; r++)
                    Ps[dx][r] = (u64)dsg[dx][r] | ((u64)dsg[dx][r + 1] << 32);
            u32 sb = 0, nb = 0;
            #pragma unroll 4
            for (int ch = 0; ch < 16; ch++) {
                u64 w0s = P[OC2 + ch * 6 + 3], w1s = P[OC2 + ch * 6 + 4];   // uniform -> SGPR
                u32 w2s = (u32)P[OC2 + ch * 6 + 5];
                u32 mn = 255;
                for (int dy = 0; dy < 2; dy++)
                    for (int dx = 0; dx < 2; dx++) {
                        u64 t0 = Ps[dx][dy] ^ w0s, t1 = Ps[dx][dy + 2] ^ w1s;
                        u32 t2v = (dy ? dsg[dx][5] : dsg[dx][4]) ^ w2s;
                        u32 c = __popcll(t0) + __popcll(t1) + __popc(t2v);
                        mn = min(mn, c);
                    }
                sb |= (mn >= 76 ? 1u : 0u) << ch;
                nb |= (mn != 75 ? 1u : 0u) << ch;
            }
            ((u16*)h2s[li])[p] = (u16)sb;
            ((u16*)h2n[li])[p] = (u16)nb;
        } else {
            u32 dn[2][6], dsg[2][6];
            for (int r = 0; r < 6; r++) {
                u64 a_n = h1An[li][y0 + r], a_s = h1As[li][y0 + r];
                u64 b_n = h1Bn[li][y0 + r], b_s = h1Bs[li][y0 + r];
                for (int dx = 0; dx < 2; dx++) {
                    int t2 = 2 * px2 + dx;
                    u64 an = a_n >> t2, as = a_s >> t2, bn = b_n >> t2, bs = b_s >> t2;
                    dn[dx][r]  = (((u32)an & 31u) | ((u32)(an >> 11) & 0x3E0u) | ((u32)(an >> 22) & 0x7C00u))
                               | ((((u32)bn & 31u) | ((u32)(bn >> 11) & 0x3E0u) | ((u32)(bn >> 22) & 0x7C00u)) << 15);
                    dsg[dx][r] = (((u32)as & 31u) | ((u32)(as >> 11) & 0x3E0u) | ((u32)(as >> 22) & 0x7C00u))
                               | ((((u32)bs & 31u) | ((u32)(bs >> 11) & 0x3E0u) | ((u32)(bs >> 22) & 0x7C00u)) << 15);
                }
            }
            u64 Pn[2][4], Ps[2][4];
            for (int dx = 0; dx < 2; dx++)
                for (int r = 0; r < 4; r++) {
                    Pn[dx][r] = (u64)dn[dx][r]  | ((u64)dn[dx][r + 1]  << 32);
                    Ps[dx][r] = (u64)dsg[dx][r] | ((u64)dsg[dx][r + 1] << 32);
                }
            u32 sb = 0, nb = 0;
            #pragma unroll 4
            for (int ch = 0; ch < 16; ch++) {
                u64 w0n = P[OC2 + ch * 6 + 0], w1n = P[OC2 + ch * 6 + 1];
                u32 w2n = (u32)P[OC2 + ch * 6 + 2];
                u64 w0s = P[OC2 + ch * 6 + 3], w1s = P[OC2 + ch * 6 + 4];
                u32 w2s = (u32)P[OC2 + ch * 6 + 5];
                int am = -1000000;
                for (int dy = 0; dy < 2; dy++)
                    for (int dx = 0; dx < 2; dx++) {
                        u64 m0 = Pn[dx][dy] & w0n, m1 = Pn[dx][dy + 2] & w1n;
                        u32 m2 = (dy ? dn[dx][5] : dn[dx][4]) & w2n;
                        u64 x0 = m0 & (Ps[dx][dy] ^ w0s), x1 = m1 & (Ps[dx][dy + 2] ^ w1s);
                        u32 x2 = m2 & ((dy ? dsg[dx][5] : dsg[dx][4]) ^ w2s);
                        int v = __popcll(m0) + __popcll(m1) + __popc(m2)
                              - 2 * (__popcll(x0) + __popcll(x1) + __popc(x2));
                        am = max(am, v);
                    }
                sb |= sgnb(am) << ch;
                nb |= nzb(am) << ch;
            }
            ((u16*)h2s[li])[p] = (u16)sb;
            ((u16*)h2n[li])[p] = (u16)nb;
        }
    }
    WB();

    // ---- fc1: 400 -> 120 (pad 128); word-outer so weights load once ----
    #pragma unroll
    for (int word = 0; word < 2; word++) {
        int j = word * 64 + lane;
        const u64* wj = P + OF1 + j * 15;
        u64 wn[7], ws[7];
        #pragma unroll
        for (int k = 0; k < 7; k++) { wn[k] = wj[k]; ws[k] = wj[7 + k]; }
        #pragma unroll
        for (int im = 0; im < 2; im++) {
            int li = li0 + im;
            int acc = 0;
            #pragma unroll
            for (int k = 0; k < 7; k++) {
                u64 m  = h2n[li][k] & wn[k];
                u64 mx = m & (h2s[li][k] ^ ws[k]);
                acc += __popcll(m) - 2 * __popcll(mx);
            }
            u64 bs = __ballot(acc < 0);
            u64 bn = __ballot(acc != 0);
            if (lane == 0) { f1s[li][word] = bs; f1n[li][word] = bn; }
        }
    }
    WB();

    // ---- fc2: 120 -> 84 (pad 128); word-outer shared weights ----
    #pragma unroll
    for (int word = 0; word < 2; word++) {
        int j = word * 64 + lane;
        const u64* wj = P + OF2 + j * 5;
        u64 a0 = wj[0], a1 = wj[1], s0 = wj[2], s1 = wj[3];
        #pragma unroll
        for (int im = 0; im < 2; im++) {
            int li = li0 + im;
            u64 m0 = f1n[li][0] & a0, m1 = f1n[li][1] & a1;
            u64 x0 = m0 & (f1s[li][0] ^ s0), x1 = m1 & (f1s[li][1] ^ s1);
            int acc = __popcll(m0) + __popcll(m1) - 2 * (__popcll(x0) + __popcll(x1));
            u64 bs = __ballot(acc < 0);
            u64 bn = __ballot(acc != 0);
            if (lane == 0) { f2s[li][word] = bs; f2n[li][word] = bn; }
        }
    }
    WB();

    // ---- fc3: 84 -> 10, fp32 out ----
    if (lane < 32) {
        int im = lane >> 4, j = lane & 15, li = li0 + im;
        if (j < 10) {
            const u64* wj = P + OF3 + j * 4;
            u64 m0 = f2n[li][0] & wj[0], m1 = f2n[li][1] & wj[1];
            u64 x0 = m0 & (f2s[li][0] ^ wj[2]), x1 = m1 & (f2s[li][1] ^ wj[3]);
            int acc = __popcll(m0) + __popcll(m1) - 2 * (__popcll(x0) + __popcll(x1));
            out[(size_t)(img0 + li) * 10 + j] = (float)acc;
        }
    }
}

extern "C" void kernel_launch(void* const* d_in, const int* in_sizes, int n_in,
                              void* d_out, int out_size, void* d_ws, size_t ws_size,
                              hipStream_t stream) {
    const float* x    = (const float*)d_in[0];
    const float* w1   = (const float*)d_in[1];
    const float* w2   = (const float*)d_in[2];
    const float* wfc1 = (const float*)d_in[3];
    const float* wfc2 = (const float*)d_in[4];
    const float* wfc3 = (const float*)d_in[5];
    float* out = (float*)d_out;
    u64* P = (u64*)d_ws;

    int B = in_sizes[0] / 1024;  // 16384

    pack_w<<<11, 256, 0, stream>>>(w1, w2, wfc1, wfc2, wfc3, P);
    lenet_main<<<B / G, 256, 0, stream>>>(x, P, out);
}

// Round 4
// 149.127 us; speedup vs baseline: 1.1311x; 1.1311x over previous
//
#include <hip/hip_runtime.h>
#include <hip/hip_bf16.h>

typedef unsigned int u32;
typedef unsigned short u16;
typedef unsigned long long u64;

// ---------------- packed-weight layout in d_ws (u64 indices) ----------------
#define OC1 0      // conv1: 3 nz ch-pair words, then 3 sign ch-pair words
#define OC2 8      // conv2: per out-ch 6 u64: [0..2]=nz rows, [3..5]=sign rows
#define WCONV 104
#define OF1 104    // fc1: per j (pad 128): 0..6 nz, 7..13 sign, 14 pad
#define OF2 2024   // fc2: per j (pad 128): [0,1] nz, [2,3] sign, [4] pad
#define OF3 2664   // fc3: per j: [0,1] nz, [2,3] sign
#define WTOT 2704

__global__ void pack_w(const float* __restrict__ w1, const float* __restrict__ w2,
                       const float* __restrict__ f1, const float* __restrict__ f2,
                       const float* __restrict__ f3, u64* __restrict__ P) {
    int g = blockIdx.x * 256 + threadIdx.x;
    if (g < 1920) {                      // fc1: j*15 + w
        int j = g / 15, w = g % 15;
        u64 v = 0;
        if (w < 14 && j < 120) {
            bool sp = (w >= 7); int k = sp ? w - 7 : w;
            for (int f = 0; f < 4; f++) {
                int p = 4 * k + f;
                if (p < 25)
                    for (int ch = 0; ch < 16; ch++) {
                        float x = f1[j * 400 + ch * 25 + p];
                        bool b = sp ? (x < 0.0f) : (x != 0.0f);
                        if (b) v |= 1ull << (f * 16 + ch);
                    }
            }
        }
        P[OF1 + g] = v;
    } else if (g < 2560) {               // fc2
        int g2 = g - 1920, j = g2 / 5, w = g2 % 5;
        u64 v = 0;
        if (w < 4 && j < 84) {
            bool sp = (w >= 2); int h = w & 1;
            for (int b = 0; b < 64; b++) {
                int k = h * 64 + b;
                if (k < 120) {
                    float x = f2[j * 120 + k];
                    bool bb = sp ? (x < 0.0f) : (x != 0.0f);
                    if (bb) v |= 1ull << b;
                }
            }
        }
        P[OF2 + g2] = v;
    } else if (g < 2600) {               // fc3
        int g3 = g - 2560, j = g3 / 4, w = g3 % 4;
        bool sp = (w >= 2); int h = w & 1;
        u64 v = 0;
        for (int b = 0; b < 64; b++) {
            int k = h * 64 + b;
            if (k < 84) {
                float x = f3[j * 84 + k];
                bool bb = sp ? (x < 0.0f) : (x != 0.0f);
                if (bb) v |= 1ull << b;
            }
        }
        P[OF3 + g3] = v;
    } else if (g < 2696) {               // conv2
        int c = g - 2600, ch = c / 6, w = c % 6;
        bool sp = (w >= 3); int wp = w % 3;
        u64 v = 0;
        for (int half = 0; half < 2; half++) {
            int r = 2 * wp + half;
            if (r < 5) {
                u32 rowv = 0;
                for (int ci = 0; ci < 6; ci++)
                    for (int cc = 0; cc < 5; cc++) {
                        float x = w2[((ch * 6 + ci) * 5 + r) * 5 + cc];
                        bool b = sp ? (x < 0.0f) : (x != 0.0f);
                        int bit = (ci < 3) ? (5 * ci + cc) : (15 + 5 * (ci - 3) + cc);
                        if (b) rowv |= 1u << bit;
                    }
                v |= (u64)rowv << (32 * half);
            }
        }
        P[OC2 + ch * 6 + (sp ? 3 : 0) + wp] = v;
    } else if (g < 2702) {               // conv1
        int c = g - 2696;
        int pair = c % 3; bool sp = (c >= 3);
        u64 v = 0;
        for (int half = 0; half < 2; half++) {
            int ch = 2 * pair + half;
            u32 wd = 0;
            for (int r = 0; r < 5; r++)
                for (int cc = 0; cc < 5; cc++) {
                    float x = w1[ch * 25 + r * 5 + cc];
                    bool b = sp ? (x < 0.0f) : (x != 0.0f);
                    if (b) wd |= 1u << (6 * r + cc);
                }
            v |= (u64)wd << (32 * half);
        }
        P[OC1 + (sp ? 3 : 0) + pair] = v;
    }
}

#define G 8  // images per block (2 per wave, 4 waves)

__device__ __forceinline__ u32 sgnb(int v) { return (u32)v >> 31; }
__device__ __forceinline__ u32 nzb(int v)  { return (u32)(v | -v) >> 31; }
// Within one wave the DS pipe is FIFO, so read-after-write through LDS needs
// only a compiler scheduling fence, not s_barrier:
#define WB() __builtin_amdgcn_wave_barrier()

// async global->LDS, 16B per lane, dest = wave-uniform base + lane*16 (HW rule)
#define GLOAD16(gp, lp) __builtin_amdgcn_global_load_lds( \
    (const __attribute__((address_space(1))) void*)(gp), \
    (__attribute__((address_space(3))) void*)(lp), 16, 0, 0)

// conv1 fast path for one image (straight-line macro: NO lambdas, no float
// arrays -> avoids the round-1/round-3 scratch-spill trap).
#define CONV1_FAST(LI) do {                                                   \
    const int px_ = lane & 15;                                                \
    const int pxe_ = px_ < 14 ? px_ : 13;                                     \
    const int tt_ = 2 * pxe_;                                                 \
    const int g_ = lane >> 4;                                                 \
    u64 c1s0_ = P[OC1 + 3], c1s1_ = P[OC1 + 4], c1s2_ = P[OC1 + 5];           \
    _Pragma("unroll")                                                         \
    for (int it_ = 0; it_ < 4; it_++) {                                       \
        int seg_ = it_ * 4 + g_;                                              \
        int py_ = seg_ < 14 ? seg_ : 13;                                      \
        int oy_ = 2 * py_;                                                    \
        u32 rs0_ = xs[LI][oy_], rs1_ = xs[LI][oy_ + 1], rs2_ = xs[LI][oy_ + 2]; \
        u32 rs3_ = xs[LI][oy_ + 3], rs4_ = xs[LI][oy_ + 4], rs5_ = xs[LI][oy_ + 5]; \
        u32 W6a_ = ((rs0_ >> tt_) & 63u) | (((rs1_ >> tt_) & 63u) << 6)       \
                 | (((rs2_ >> tt_) & 63u) << 12) | (((rs3_ >> tt_) & 63u) << 18) \
                 | (((rs4_ >> tt_) & 63u) << 24);                             \
        u32 W6b_ = (W6a_ >> 6) | (((rs5_ >> tt_) & 63u) << 24);               \
        u32 c0_ = 255, c1_ = 255, c2_ = 255, c3_ = 255, c4_ = 255, c5_ = 255; \
        _Pragma("unroll")                                                     \
        for (int dy_ = 0; dy_ < 2; dy_++) {                                   \
            u32 base_ = dy_ ? W6b_ : W6a_;                                    \
            _Pragma("unroll")                                                 \
            for (int dx_ = 0; dx_ < 2; dx_++) {                               \
                u32 w_ = (dx_ ? (base_ >> 1) : base_) & 0x1F7DF7DFu;          \
                u64 W_ = ((u64)w_ << 32) | w_;                                \
                u64 t0_ = W_ ^ c1s0_;                                         \
                c0_ = min(c0_, (u32)__popc((u32)t0_));                        \
                c1_ = min(c1_, (u32)__popc((u32)(t0_ >> 32)));                \
                u64 t1_ = W_ ^ c1s1_;                                         \
                c2_ = min(c2_, (u32)__popc((u32)t1_));                        \
                c3_ = min(c3_, (u32)__popc((u32)(t1_ >> 32)));                \
                u64 t2_ = W_ ^ c1s2_;                                         \
                c4_ = min(c4_, (u32)__popc((u32)t2_));                        \
                c5_ = min(c5_, (u32)__popc((u32)(t2_ >> 32)));                \
            }                                                                 \
        }                                                                     \
        u64 b0_ = __ballot(c0_ >= 13), b1_ = __ballot(c1_ >= 13);             \
        u64 b2_ = __ballot(c2_ >= 13), b3_ = __ballot(c3_ >= 13);             \
        u64 b4_ = __ballot(c4_ >= 13), b5_ = __ballot(c5_ >= 13);             \
        if (px_ == 0 && seg_ < 14) {                                          \
            int sh_ = lane & 48;                                              \
            h1As[LI][seg_] = ((b0_ >> sh_) & 0x3FFF) | (((b1_ >> sh_) & 0x3FFF) << 16) | (((b2_ >> sh_) & 0x3FFF) << 32); \
            h1Bs[LI][seg_] = ((b3_ >> sh_) & 0x3FFF) | (((b4_ >> sh_) & 0x3FFF) << 16) | (((b5_ >> sh_) & 0x3FFF) << 32); \
        }                                                                     \
    }                                                                         \
} while (0)

// conv1 slow path (zero-containing inputs): register-light, re-reads LDS.
#define CONV1_SLOW(LI) do {                                                   \
    const int px_ = lane & 15;                                                \
    const int pxe_ = px_ < 14 ? px_ : 13;                                     \
    const int tt_ = 2 * pxe_;                                                 \
    const int g_ = lane >> 4;                                                 \
    for (int it_ = 0; it_ < 4; it_++) {                                       \
        int seg_ = it_ * 4 + g_;                                              \
        int py_ = seg_ < 14 ? seg_ : 13;                                      \
        int oy_ = 2 * py_;                                                    \
        int best_[6];                                                         \
        for (int c_ = 0; c_ < 6; c_++) best_[c_] = -1000;                     \
        for (int dy_ = 0; dy_ < 2; dy_++)                                     \
            for (int dx_ = 0; dx_ < 2; dx_++) {                               \
                u32 wn_ = 0, ws_ = 0;                                         \
                for (int r_ = 0; r_ < 5; r_++) {                              \
                    u32 an_ = xn[LI][oy_ + dy_ + r_], as_ = xs[LI][oy_ + dy_ + r_]; \
                    wn_ |= ((an_ >> (tt_ + dx_)) & 31u) << (6 * r_);          \
                    ws_ |= ((as_ >> (tt_ + dx_)) & 31u) << (6 * r_);          \
                }                                                             \
                u64 Wn_ = ((u64)wn_ << 32) | wn_;                             \
                u64 Ws_ = ((u64)ws_ << 32) | ws_;                             \
                for (int p_ = 0; p_ < 3; p_++) {                              \
                    u64 cn_ = P[OC1 + p_], cs_ = P[OC1 + 3 + p_];             \
                    u64 m_ = Wn_ & cn_;                                       \
                    u64 mx_ = m_ & (Ws_ ^ cs_);                               \
                    int a0_ = __popc((u32)m_) - 2 * __popc((u32)mx_);         \
                    int a1_ = __popc((u32)(m_ >> 32)) - 2 * __popc((u32)(mx_ >> 32)); \
                    best_[2 * p_]     = max(best_[2 * p_], a0_);              \
                    best_[2 * p_ + 1] = max(best_[2 * p_ + 1], a1_);          \
                }                                                             \
            }                                                                 \
        u64 bS_[6], bN_[6];                                                   \
        for (int c_ = 0; c_ < 6; c_++) {                                      \
            bS_[c_] = __ballot(best_[c_] < 0);                                \
            bN_[c_] = __ballot(best_[c_] != 0);                               \
        }                                                                     \
        if (px_ == 0 && seg_ < 14) {                                          \
            int sh_ = lane & 48;                                              \
            h1As[LI][seg_] = ((bS_[0] >> sh_) & 0x3FFF) | (((bS_[1] >> sh_) & 0x3FFF) << 16) | (((bS_[2] >> sh_) & 0x3FFF) << 32); \
            h1An[LI][seg_] = ((bN_[0] >> sh_) & 0x3FFF) | (((bN_[1] >> sh_) & 0x3FFF) << 16) | (((bN_[2] >> sh_) & 0x3FFF) << 32); \
            h1Bs[LI][seg_] = ((bS_[3] >> sh_) & 0x3FFF) | (((bS_[4] >> sh_) & 0x3FFF) << 16) | (((bS_[5] >> sh_) & 0x3FFF) << 32); \
            h1Bn[LI][seg_] = ((bN_[3] >> sh_) & 0x3FFF) | (((bN_[4] >> sh_) & 0x3FFF) << 16) | (((bN_[5] >> sh_) & 0x3FFF) << 32); \
        }                                                                     \
    }                                                                         \
} while (0)

// Per wave: async-stage image B floats to LDS (global_load_lds, zero VGPRs)
// -> load+pack A (VGPR float4, consumed immediately) -> conv1(A) while B
// streams -> vmcnt(0) -> pack B from LDS -> conv1(B) -> conv2 -> fc.
// LDS 23.4 KB -> 6 blocks/CU: 2048-block grid backfills 2 blocks/CU, which
// staggers the input-load bursts instead of one synchronized t=0 burst.
__global__ __launch_bounds__(256, 6) void lenet_main(const float* __restrict__ X,
                                                     const u64* __restrict__ P,
                                                     float* __restrict__ out) {
    __shared__ __align__(16) float stage[4][1024];   // per-wave image-B floats
    __shared__ u32 xs[G][32], xn[G][32];
    __shared__ u64 h1An[G][14], h1As[G][14], h1Bn[G][14], h1Bs[G][14];
    __shared__ u64 h2n[G][7], h2s[G][7];
    __shared__ u64 f1s[G][2], f1n[G][2], f2s[G][2], f2n[G][2];

    const int tid = threadIdx.x;
    const int wid = tid >> 6, lane = tid & 63;
    const int img0 = blockIdx.x * G;
    const int liA = wid * 2, liB = liA + 1;
    const int li0 = liA;

    const float4* X4 = (const float4*)(X + (size_t)img0 * 1024);

    // ---- issue async LDS staging of image B (4 x 1KB, no VGPR cost) ----
    {
        const float* gB = X + ((size_t)img0 + liB) * 1024;
        GLOAD16(gB + 0 * 256 + lane * 4, &stage[wid][0 * 256]);
        GLOAD16(gB + 1 * 256 + lane * 4, &stage[wid][1 * 256]);
        GLOAD16(gB + 2 * 256 + lane * 4, &stage[wid][2 * 256]);
        GLOAD16(gB + 3 * 256 + lane * 4, &stage[wid][3 * 256]);
    }

    // ---- weight cleanliness (no exact-0 conv weights), wave-uniform ----
    u64 db;
    {
        bool bad = false;
        if (lane < 51) {
            u64 w, exp;
            if (lane < 48) {
                int ch = lane / 3, k = lane % 3;
                w = P[OC2 + ch * 6 + k];
                exp = (k < 2) ? 0x3FFFFFFF3FFFFFFFull : 0x000000003FFFFFFFull;
            } else {
                w = P[OC1 + (lane - 48)];
                exp = 0x1F7DF7DF1F7DF7DFull;
            }
            bad = (w != exp);
        }
        db = __ballot(bad);
    }

    // ---- pack A: float4 load (consumed immediately) + shfl-xor pack ----
    u32 naccA = 15u;
    #pragma unroll
    for (int it = 0; it < 4; it++) {
        float4 v = X4[liA * 256 + it * 64 + lane];
        u32 s = (v.x < 0.0f ? 1u : 0u) | (v.y < 0.0f ? 2u : 0u)
              | (v.z < 0.0f ? 4u : 0u) | (v.w < 0.0f ? 8u : 0u);
        u32 n = (v.x != 0.0f ? 1u : 0u) | (v.y != 0.0f ? 2u : 0u)
              | (v.z != 0.0f ? 4u : 0u) | (v.w != 0.0f ? 8u : 0u);
        naccA &= n;
        u32 sw = s << (4 * (lane & 7)), nw = n << (4 * (lane & 7));
        sw |= __shfl_xor((int)sw, 1); sw |= __shfl_xor((int)sw, 2); sw |= __shfl_xor((int)sw, 4);
        nw |= __shfl_xor((int)nw, 1); nw |= __shfl_xor((int)nw, 2); nw |= __shfl_xor((int)nw, 4);
        if ((lane & 7) == 0) { xs[liA][it * 8 + (lane >> 3)] = sw; xn[liA][it * 8 + (lane >> 3)] = nw; }
    }
    const bool fpA = ((__ballot(naccA != 15u) | db) == 0);
    WB();

    // ---- conv1(A); image-B DMA streams underneath ----
    if (fpA) CONV1_FAST(liA); else CONV1_SLOW(liA);

    // ---- wait for staged B, then pack B from LDS ----
    asm volatile("s_waitcnt vmcnt(0)" ::: "memory");
    __builtin_amdgcn_sched_barrier(0);
    u32 naccB = 15u;
    #pragma unroll
    for (int it = 0; it < 4; it++) {
        float4 v = *(const float4*)&stage[wid][it * 256 + lane * 4];
        u32 s = (v.x < 0.0f ? 1u : 0u) | (v.y < 0.0f ? 2u : 0u)
              | (v.z < 0.0f ? 4u : 0u) | (v.w < 0.0f ? 8u : 0u);
        u32 n = (v.x != 0.0f ? 1u : 0u) | (v.y != 0.0f ? 2u : 0u)
              | (v.z != 0.0f ? 4u : 0u) | (v.w != 0.0f ? 8u : 0u);
        naccB &= n;
        u32 sw = s << (4 * (lane & 7)), nw = n << (4 * (lane & 7));
        sw |= __shfl_xor((int)sw, 1); sw |= __shfl_xor((int)sw, 2); sw |= __shfl_xor((int)sw, 4);
        nw |= __shfl_xor((int)nw, 1); nw |= __shfl_xor((int)nw, 2); nw |= __shfl_xor((int)nw, 4);
        if ((lane & 7) == 0) { xs[liB][it * 8 + (lane >> 3)] = sw; xn[liB][it * 8 + (lane >> 3)] = nw; }
    }
    const bool fpB = ((__ballot(naccB != 15u) | db) == 0);
    WB();
    if (fpB) CONV1_FAST(liB); else CONV1_SLOW(liB);
    WB();

    // ---- conv2 + pool: 50 lanes (2 img x 25 points); per-lane u16 stores ----
    if (lane < 6) {   // zero the 3 pad halfwords (u16 idx 25..27) per image
        int li = li0 + (lane >= 3 ? 1 : 0); int t = lane % 3;
        ((u16*)h2n[li])[25 + t] = 0; ((u16*)h2s[li])[25 + t] = 0;
    }
    if (lane < 50) {
        int im = lane >= 25 ? 1 : 0, p = lane - 25 * im, li = li0 + im;
        bool cfast = im ? fpB : fpA;
        int py = p / 5, px2 = p % 5;
        int y0 = 2 * py;
        if (cfast) {
            u32 dsg[2][6];
            for (int r = 0; r < 6; r++) {
                u64 a = h1As[li][y0 + r], b = h1Bs[li][y0 + r];
                for (int dx = 0; dx < 2; dx++) {
                    int t2 = 2 * px2 + dx;
                    u64 as = a >> t2, bs = b >> t2;
                    dsg[dx][r] = (((u32)as & 31u) | ((u32)(as >> 11) & 0x3E0u) | ((u32)(as >> 22) & 0x7C00u))
                               | ((((u32)bs & 31u) | ((u32)(bs >> 11) & 0x3E0u) | ((u32)(bs >> 22) & 0x7C00u)) << 15);
                }
            }
            u64 Ps[2][4];
            for (int dx = 0; dx < 2; dx++)
                for (int r = 0; r < 4; r++)
                    Ps[dx][r] = (u64)dsg[dx][r] | ((u64)dsg[dx][r + 1] << 32);
            u32 sb = 0, nb = 0;
            #pragma unroll 4
            for (int ch = 0; ch < 16; ch++) {
                u64 w0s = P[OC2 + ch * 6 + 3], w1s = P[OC2 + ch * 6 + 4];   // uniform -> SGPR
                u32 w2s = (u32)P[OC2 + ch * 6 + 5];
                u32 mn = 255;
                for (int dy = 0; dy < 2; dy++)
                    for (int dx = 0; dx < 2; dx++) {
                        u64 t0 = Ps[dx][dy] ^ w0s, t1 = Ps[dx][dy + 2] ^ w1s;
                        u32 t2v = (dy ? dsg[dx][5] : dsg[dx][4]) ^ w2s;
                        u32 c = __popcll(t0) + __popcll(t1) + __popc(t2v);
                        mn = min(mn, c);
                    }
                sb |= (mn >= 76 ? 1u : 0u) << ch;
                nb |= (mn != 75 ? 1u : 0u) << ch;
            }
            ((u16*)h2s[li])[p] = (u16)sb;
            ((u16*)h2n[li])[p] = (u16)nb;
        } else {
            u32 dn[2][6], dsg[2][6];
            for (int r = 0; r < 6; r++) {
                u64 a_n = h1An[li][y0 + r], a_s = h1As[li][y0 + r];
                u64 b_n = h1Bn[li][y0 + r], b_s = h1Bs[li][y0 + r];
                for (int dx = 0; dx < 2; dx++) {
                    int t2 = 2 * px2 + dx;
                    u64 an = a_n >> t2, as = a_s >> t2, bn = b_n >> t2, bs = b_s >> t2;
                    dn[dx][r]  = (((u32)an & 31u) | ((u32)(an >> 11) & 0x3E0u) | ((u32)(an >> 22) & 0x7C00u))
                               | ((((u32)bn & 31u) | ((u32)(bn >> 11) & 0x3E0u) | ((u32)(bn >> 22) & 0x7C00u)) << 15);
                    dsg[dx][r] = (((u32)as & 31u) | ((u32)(as >> 11) & 0x3E0u) | ((u32)(as >> 22) & 0x7C00u))
                               | ((((u32)bs & 31u) | ((u32)(bs >> 11) & 0x3E0u) | ((u32)(bs >> 22) & 0x7C00u)) << 15);
                }
            }
            u64 Pn[2][4], Ps[2][4];
            for (int dx = 0; dx < 2; dx++)
                for (int r = 0; r < 4; r++) {
                    Pn[dx][r] = (u64)dn[dx][r]  | ((u64)dn[dx][r + 1]  << 32);
                    Ps[dx][r] = (u64)dsg[dx][r] | ((u64)dsg[dx][r + 1] << 32);
                }
            u32 sb = 0, nb = 0;
            #pragma unroll 4
            for (int ch = 0; ch < 16; ch++) {
                u64 w0n = P[OC2 + ch * 6 + 0], w1n = P[OC2 + ch * 6 + 1];
                u32 w2n = (u32)P[OC2 + ch * 6 + 2];
                u64 w0s = P[OC2 + ch * 6 + 3], w1s = P[OC2 + ch * 6 + 4];
                u32 w2s = (u32)P[OC2 + ch * 6 + 5];
                int am = -1000000;
                for (int dy = 0; dy < 2; dy++)
                    for (int dx = 0; dx < 2; dx++) {
                        u64 m0 = Pn[dx][dy] & w0n, m1 = Pn[dx][dy + 2] & w1n;
                        u32 m2 = (dy ? dn[dx][5] : dn[dx][4]) & w2n;
                        u64 x0 = m0 & (Ps[dx][dy] ^ w0s), x1 = m1 & (Ps[dx][dy + 2] ^ w1s);
                        u32 x2 = m2 & ((dy ? dsg[dx][5] : dsg[dx][4]) ^ w2s);
                        int v = __popcll(m0) + __popcll(m1) + __popc(m2)
                              - 2 * (__popcll(x0) + __popcll(x1) + __popc(x2));
                        am = max(am, v);
                    }
                sb |= sgnb(am) << ch;
                nb |= nzb(am) << ch;
            }
            ((u16*)h2s[li])[p] = (u16)sb;
            ((u16*)h2n[li])[p] = (u16)nb;
        }
    }
    WB();

    // ---- fc1: 400 -> 120 (pad 128); word-outer so weights load once ----
    #pragma unroll
    for (int word = 0; word < 2; word++) {
        int j = word * 64 + lane;
        const u64* wj = P + OF1 + j * 15;
        u64 wn[7], ws[7];
        #pragma unroll
        for (int k = 0; k < 7; k++) { wn[k] = wj[k]; ws[k] = wj[7 + k]; }
        #pragma unroll
        for (int im = 0; im < 2; im++) {
            int li = li0 + im;
            int acc = 0;
            #pragma unroll
            for (int k = 0; k < 7; k++) {
                u64 m  = h2n[li][k] & wn[k];
                u64 mx = m & (h2s[li][k] ^ ws[k]);
                acc += __popcll(m) - 2 * __popcll(mx);
            }
            u64 bs = __ballot(acc < 0);
            u64 bn = __ballot(acc != 0);
            if (lane == 0) { f1s[li][word] = bs; f1n[li][word] = bn; }
        }
    }
    WB();

    // ---- fc2: 120 -> 84 (pad 128); word-outer shared weights ----
    #pragma unroll
    for (int word = 0; word < 2; word++) {
        int j = word * 64 + lane;
        const u64* wj = P + OF2 + j * 5;
        u64 a0 = wj[0], a1 = wj[1], s0 = wj[2], s1 = wj[3];
        #pragma unroll
        for (int im = 0; im < 2; im++) {
            int li = li0 + im;
            u64 m0 = f1n[li][0] & a0, m1 = f1n[li][1] & a1;
            u64 x0 = m0 & (f1s[li][0] ^ s0), x1 = m1 & (f1s[li][1] ^ s1);
            int acc = __popcll(m0) + __popcll(m1) - 2 * (__popcll(x0) + __popcll(x1));
            u64 bs = __ballot(acc < 0);
            u64 bn = __ballot(acc != 0);
            if (lane == 0) { f2s[li][word] = bs; f2n[li][word] = bn; }
        }
    }
    WB();

    // ---- fc3: 84 -> 10, fp32 out ----
    if (lane < 32) {
        int im = lane >> 4, j = lane & 15, li = li0 + im;
        if (j < 10) {
            const u64* wj = P + OF3 + j * 4;
            u64 m0 = f2n[li][0] & wj[0], m1 = f2n[li][1] & wj[1];
            u64 x0 = m0 & (f2s[li][0] ^ wj[2]), x1 = m1 & (f2s[li][1] ^ wj[3]);
            int acc = __popcll(m0) + __popcll(m1) - 2 * (__popcll(x0) + __popcll(x1));
            out[(size_t)(img0 + li) * 10 + j] = (float)acc;
        }
    }
}

extern "C" void kernel_launch(void* const* d_in, const int* in_sizes, int n_in,
                              void* d_out, int out_size, void* d_ws, size_t ws_size,
                              hipStream_t stream) {
    const float* x    = (const float*)d_in[0];
    const float* w1   = (const float*)d_in[1];
    const float* w2   = (const float*)d_in[2];
    const float* wfc1 = (const float*)d_in[3];
    const float* wfc2 = (const float*)d_in[4];
    const float* wfc3 = (const float*)d_in[5];
    float* out = (float*)d_out;
    u64* P = (u64*)d_ws;

    int B = in_sizes[0] / 1024;  // 16384

    pack_w<<<11, 256, 0, stream>>>(w1, w2, wfc1, wfc2, wfc3, P);
    lenet_main<<<B / G, 256, 0, stream>>>(x, P, out);
}